// Round 4
// baseline (461.879 us; speedup 1.0000x reference)
//
#include <hip/hip_runtime.h>

// LeNet forward, BATCH=4096, all-fp32. trunc = zero low 13 mantissa bits.
// ws layout (floats): p1[4096*2880] | p2[4096*800] | h1[4096*500]  (~69 MB)

__device__ __forceinline__ float trunc13(float v) {
    return __int_as_float(__float_as_int(v) & (int)0xFFFFE000u);
}

// ---------------------------------------------------------------------------
// K1: conv1 (1->20, 5x5, VALID) + bias + trunc + relu + 2x2 maxpool
// ---------------------------------------------------------------------------
__global__ __launch_bounds__(256) void k_conv1(const float* __restrict__ x,
                                               const float* __restrict__ w1,
                                               const float* __restrict__ b1,
                                               float* __restrict__ p1) {
    __shared__ float wsm[500];
    __shared__ float bsm[20];
    int tid = threadIdx.x;
    for (int t = tid; t < 500; t += 256) wsm[t] = w1[t];
    if (tid < 20) bsm[tid] = b1[tid];
    __syncthreads();

    int gid = blockIdx.x * 256 + tid;   // 4096*144 = 589824 = 2304*256 exact
    int b   = gid / 144;
    int pos = gid % 144;
    int py = pos / 12, px = pos % 12;
    const float* img = x + (size_t)b * 784;

    float patch[36];
#pragma unroll
    for (int r = 0; r < 6; ++r)
#pragma unroll
        for (int c = 0; c < 6; ++c)
            patch[r * 6 + c] = img[(2 * py + r) * 28 + 2 * px + c];

    float* outp = p1 + (size_t)b * 2880 + pos;
    for (int oc = 0; oc < 20; ++oc) {
        float bias = bsm[oc];
        float s00 = bias, s01 = bias, s10 = bias, s11 = bias;
        const float* w = &wsm[oc * 25];
#pragma unroll
        for (int ky = 0; ky < 5; ++ky)
#pragma unroll
            for (int kx = 0; kx < 5; ++kx) {
                float wv = w[ky * 5 + kx];
                s00 += patch[ky * 6 + kx] * wv;
                s01 += patch[ky * 6 + kx + 1] * wv;
                s10 += patch[(ky + 1) * 6 + kx] * wv;
                s11 += patch[(ky + 1) * 6 + kx + 1] * wv;
            }
        float m = fmaxf(fmaxf(fmaxf(trunc13(s00), 0.f), fmaxf(trunc13(s01), 0.f)),
                        fmaxf(fmaxf(trunc13(s10), 0.f), fmaxf(trunc13(s11), 0.f)));
        outp[oc * 144] = m;
    }
}

// ---------------------------------------------------------------------------
// K2: conv2 (20->50, 5x5) + bias + trunc + relu + 2x2 maxpool
// 512 thr = 8 waves per block of 4 LDS-staged images; wave w owns oc group
// [7w, 7w+7) (56>=50, clamped+guarded). Lane = img*16 + pooled pos.
// Weights: wave-uniform offsets (readfirstlane) -> SGPR s_loads, explicitly
// DOUBLE-BUFFERED (wA/wB) so the next step's loads issue before the current
// 100-FMA block -> L2 latency hidden. 3 blocks/CU (LDS) = 24 waves/CU.
// ---------------------------------------------------------------------------
#define IMG_STRIDE 2888

__device__ __forceinline__ void wload(float (&w)[25], const float* __restrict__ w2,
                                      int ic, int oc) {
    int ocw = (oc < 50) ? oc : 0;
    int woff = __builtin_amdgcn_readfirstlane(ocw * 500 + ic * 25);
#pragma unroll
    for (int k = 0; k < 25; ++k) w[k] = w2[woff + k];
}

__device__ __forceinline__ void fma25(const float (&w)[25], const float (&patch)[36],
                                      float (&a)[4]) {
#pragma unroll
    for (int ky = 0; ky < 5; ++ky)
#pragma unroll
        for (int kx = 0; kx < 5; ++kx) {
            float wv = w[ky * 5 + kx];
            a[0] += patch[ky * 6 + kx] * wv;
            a[1] += patch[ky * 6 + kx + 1] * wv;
            a[2] += patch[(ky + 1) * 6 + kx] * wv;
            a[3] += patch[(ky + 1) * 6 + kx + 1] * wv;
        }
}

__device__ __forceinline__ void ldpatch(float (&patch)[36], const float* ip) {
#pragma unroll
    for (int r = 0; r < 6; ++r)
#pragma unroll
        for (int c = 0; c < 3; ++c) {
            float2 v = *reinterpret_cast<const float2*>(ip + r * 12 + 2 * c);
            patch[r * 6 + 2 * c]     = v.x;
            patch[r * 6 + 2 * c + 1] = v.y;
        }
}

__global__ __launch_bounds__(512) void k_conv2(const float* __restrict__ p1,
                                               const float* __restrict__ w2,
                                               const float* __restrict__ b2,
                                               float* __restrict__ p2) {
    __shared__ float in0[4 * IMG_STRIDE];
    int b0 = blockIdx.x * 4;
    int tid = threadIdx.x;
#pragma unroll
    for (int i4 = 0; i4 < 4; ++i4) {
        const float4* src = reinterpret_cast<const float4*>(p1 + (size_t)(b0 + i4) * 2880);
        float4* dst = reinterpret_cast<float4*>(&in0[i4 * IMG_STRIDE]);
        for (int t = tid; t < 720; t += 512) dst[t] = src[t];
    }
    __syncthreads();

    int wid  = tid >> 6;        // 0..7 -> oc group base wid*7
    int lane = tid & 63;
    int img  = lane >> 4;
    int pos  = lane & 15;
    int py = pos >> 2, px = pos & 3;
    const float* ibase = &in0[img * IMG_STRIDE + 2 * py * 12 + 2 * px];
    int ocb = wid * 7;

    float acc[7][4];
#pragma unroll
    for (int j = 0; j < 7; ++j)
#pragma unroll
        for (int q = 0; q < 4; ++q) acc[j][q] = 0.f;

    float wA[25], wB[25];
    float patch[36];
    wload(wA, w2, 0, ocb);                 // (ic=0, j=0) primed in wA

    for (int ic = 0; ic < 20; ic += 2) {
        int ic2 = (ic + 2 < 20) ? ic + 2 : 0;   // clamp for final prefetch
        // ---- first half: ic (even step parity: j0 in wA) ----
        ldpatch(patch, ibase + ic * 144);
        wload(wB, w2, ic, ocb + 1);  fma25(wA, patch, acc[0]);
        wload(wA, w2, ic, ocb + 2);  fma25(wB, patch, acc[1]);
        wload(wB, w2, ic, ocb + 3);  fma25(wA, patch, acc[2]);
        wload(wA, w2, ic, ocb + 4);  fma25(wB, patch, acc[3]);
        wload(wB, w2, ic, ocb + 5);  fma25(wA, patch, acc[4]);
        wload(wA, w2, ic, ocb + 6);  fma25(wB, patch, acc[5]);
        wload(wB, w2, ic + 1, ocb);  fma25(wA, patch, acc[6]);
        // ---- second half: ic+1 (odd parity: j0 in wB) ----
        ldpatch(patch, ibase + (ic + 1) * 144);
        wload(wA, w2, ic + 1, ocb + 1);  fma25(wB, patch, acc[0]);
        wload(wB, w2, ic + 1, ocb + 2);  fma25(wA, patch, acc[1]);
        wload(wA, w2, ic + 1, ocb + 3);  fma25(wB, patch, acc[2]);
        wload(wB, w2, ic + 1, ocb + 4);  fma25(wA, patch, acc[3]);
        wload(wA, w2, ic + 1, ocb + 5);  fma25(wB, patch, acc[4]);
        wload(wB, w2, ic + 1, ocb + 6);  fma25(wA, patch, acc[5]);
        wload(wA, w2, ic2, ocb);         fma25(wB, patch, acc[6]);
        // invariant restored: next ic's j0 is in wA
    }

#pragma unroll
    for (int j = 0; j < 7; ++j) {
        int oc = ocb + j;
        if (oc < 50) {
            float bias = b2[oc];
            float m = fmaxf(fmaxf(fmaxf(trunc13(acc[j][0] + bias), 0.f),
                                  fmaxf(trunc13(acc[j][1] + bias), 0.f)),
                            fmaxf(fmaxf(trunc13(acc[j][2] + bias), 0.f),
                                  fmaxf(trunc13(acc[j][3] + bias), 0.f)));
            p2[(size_t)(b0 + img) * 800 + oc * 16 + pos] = m;
        }
    }
}

// ---------------------------------------------------------------------------
// K3: fc1  H = relu(trunc(A @ W^T + b))   A:[4096,800] W:[500,800] -> [4096,500]
// ---------------------------------------------------------------------------
__global__ __launch_bounds__(256) void k_fc1(const float* __restrict__ A,
                                             const float* __restrict__ W,
                                             const float* __restrict__ bias,
                                             float* __restrict__ H) {
    __shared__ __align__(16) float As[16][68];
    __shared__ __align__(16) float Ws[16][68];
    int tid = threadIdx.x;
    int tx = tid & 15;
    int ty = tid >> 4;
    int i0 = blockIdx.x * 64;
    int n0 = blockIdx.y * 64;
    int tm = tid & 15;
    int tn = tid >> 4;
    float acc[4][4] = {};

    for (int k0 = 0; k0 < 800; k0 += 16) {
#pragma unroll
        for (int q = 0; q < 4; ++q) {
            int row = ty + 16 * q;
            As[tx][row] = A[(size_t)(i0 + row) * 800 + k0 + tx];
            int n = n0 + row;
            Ws[tx][row] = (n < 500) ? W[(size_t)n * 800 + k0 + tx] : 0.f;
        }
        __syncthreads();
#pragma unroll
        for (int k = 0; k < 16; ++k) {
            float4 a = *reinterpret_cast<const float4*>(&As[k][tm * 4]);
            float4 w = *reinterpret_cast<const float4*>(&Ws[k][tn * 4]);
            float av[4] = {a.x, a.y, a.z, a.w};
            float wv[4] = {w.x, w.y, w.z, w.w};
#pragma unroll
            for (int r = 0; r < 4; ++r)
#pragma unroll
                for (int c = 0; c < 4; ++c)
                    acc[r][c] += av[r] * wv[c];
        }
        __syncthreads();
    }

#pragma unroll
    for (int r = 0; r < 4; ++r) {
        int i = i0 + tm * 4 + r;
#pragma unroll
        for (int c = 0; c < 4; ++c) {
            int n = n0 + tn * 4 + c;
            if (n < 500)
                H[(size_t)i * 500 + n] = fmaxf(trunc13(acc[r][c] + bias[n]), 0.f);
        }
    }
}

// ---------------------------------------------------------------------------
// K4: fc2 (500->10) + bias + trunc + log_softmax.  One wave per row.
// ---------------------------------------------------------------------------
__global__ __launch_bounds__(256) void k_fc2(const float* __restrict__ H,
                                             const float* __restrict__ W,
                                             const float* __restrict__ bias,
                                             float* __restrict__ out) {
    int wave = threadIdx.x >> 6;
    int lane = threadIdx.x & 63;
    int i = blockIdx.x * 4 + wave;
    const float* hrow = H + (size_t)i * 500;

    float p[10];
#pragma unroll
    for (int j = 0; j < 10; ++j) p[j] = 0.f;
    for (int k = lane; k < 500; k += 64) {
        float h = hrow[k];
#pragma unroll
        for (int j = 0; j < 10; ++j) p[j] += h * W[j * 500 + k];
    }
#pragma unroll
    for (int j = 0; j < 10; ++j)
#pragma unroll
        for (int off = 32; off; off >>= 1) p[j] += __shfl_xor(p[j], off, 64);

    if (lane == 0) {
        float z[10], m = -1e30f;
#pragma unroll
        for (int j = 0; j < 10; ++j) {
            z[j] = trunc13(p[j] + bias[j]);
            m = fmaxf(m, z[j]);
        }
        float s = 0.f;
#pragma unroll
        for (int j = 0; j < 10; ++j) s += expf(z[j] - m);
        float lse = m + logf(s);
#pragma unroll
        for (int j = 0; j < 10; ++j) out[(size_t)i * 10 + j] = z[j] - lse;
    }
}

// ---------------------------------------------------------------------------
extern "C" void kernel_launch(void* const* d_in, const int* in_sizes, int n_in,
                              void* d_out, int out_size, void* d_ws, size_t ws_size,
                              hipStream_t stream) {
    const float* x   = (const float*)d_in[0];
    const float* w1  = (const float*)d_in[1];
    const float* b1  = (const float*)d_in[2];
    const float* w2  = (const float*)d_in[3];
    const float* b2  = (const float*)d_in[4];
    const float* wf1 = (const float*)d_in[5];
    const float* bf1 = (const float*)d_in[6];
    const float* wf2 = (const float*)d_in[7];
    const float* bf2 = (const float*)d_in[8];
    float* out = (float*)d_out;

    float* p1 = (float*)d_ws;                        // 4096*2880
    float* p2 = p1 + (size_t)4096 * 2880;            // 4096*800
    float* h1 = p2 + (size_t)4096 * 800;             // 4096*500

    k_conv1<<<2304, 256, 0, stream>>>(x, w1, b1, p1);
    k_conv2<<<1024, 512, 0, stream>>>(p1, w2, b2, p2);
    dim3 g3(64, 8);
    k_fc1<<<g3, 256, 0, stream>>>(p2, wf1, bf1, h1);
    k_fc2<<<1024, 256, 0, stream>>>(h1, wf2, bf2, out);
}

// Round 8
// 356.438 us; speedup vs baseline: 1.2958x; 1.2958x over previous
//
#include <hip/hip_runtime.h>

// LeNet forward, BATCH=4096, all-fp32. trunc = zero low 13 mantissa bits.
// ws layout (floats): p1[4096*2880] | p2[4096*800] | h1[4096*500]  (~69 MB)

__device__ __forceinline__ float trunc13(float v) {
    return __int_as_float(__float_as_int(v) & (int)0xFFFFE000u);
}

// ---------------------------------------------------------------------------
// K1: conv1 (1->20, 5x5, VALID) + bias + trunc + relu + 2x2 maxpool
// ---------------------------------------------------------------------------
__global__ __launch_bounds__(256) void k_conv1(const float* __restrict__ x,
                                               const float* __restrict__ w1,
                                               const float* __restrict__ b1,
                                               float* __restrict__ p1) {
    __shared__ float wsm[500];
    __shared__ float bsm[20];
    int tid = threadIdx.x;
    for (int t = tid; t < 500; t += 256) wsm[t] = w1[t];
    if (tid < 20) bsm[tid] = b1[tid];
    __syncthreads();

    int gid = blockIdx.x * 256 + tid;   // 4096*144 = 589824 = 2304*256 exact
    int b   = gid / 144;
    int pos = gid % 144;
    int py = pos / 12, px = pos % 12;
    const float* img = x + (size_t)b * 784;

    float patch[36];
#pragma unroll
    for (int r = 0; r < 6; ++r)
#pragma unroll
        for (int c = 0; c < 6; ++c)
            patch[r * 6 + c] = img[(2 * py + r) * 28 + 2 * px + c];

    float* outp = p1 + (size_t)b * 2880 + pos;
    for (int oc = 0; oc < 20; ++oc) {
        float bias = bsm[oc];
        float s00 = bias, s01 = bias, s10 = bias, s11 = bias;
        const float* w = &wsm[oc * 25];
#pragma unroll
        for (int ky = 0; ky < 5; ++ky)
#pragma unroll
            for (int kx = 0; kx < 5; ++kx) {
                float wv = w[ky * 5 + kx];
                s00 += patch[ky * 6 + kx] * wv;
                s01 += patch[ky * 6 + kx + 1] * wv;
                s10 += patch[(ky + 1) * 6 + kx] * wv;
                s11 += patch[(ky + 1) * 6 + kx + 1] * wv;
            }
        float m = fmaxf(fmaxf(fmaxf(trunc13(s00), 0.f), fmaxf(trunc13(s01), 0.f)),
                        fmaxf(fmaxf(trunc13(s10), 0.f), fmaxf(trunc13(s11), 0.f)));
        outp[oc * 144] = m;
    }
}

// ---------------------------------------------------------------------------
// K2: conv2 (20->50, 5x5) + bias + trunc + relu + 2x2 maxpool
// 256 thr = 4 waves per block of 4 LDS-staged images; wave w owns oc group
// [13w, 13w+13) (52>=50). Lane = img*16 + pooled pos.
// Weights: wave-uniform (readfirstlane) SGPR s_loads, double-buffered with
// COMPILE-TIME parity over a 26-step unrolled (2 ic x 13 oc) chain so each
// step's s_load overlaps the previous step's 100-FMA block.
// 256 threads (NOT 512): keeps regalloc at ~100 VGPR, no spills (R4 lesson).
// ---------------------------------------------------------------------------
#define IMG_STRIDE 2888

__device__ __forceinline__ void wload(float (&w)[25], const float* __restrict__ w2,
                                      int ic, int oc) {
    int ocw = (oc < 50) ? oc : 0;
    int woff = __builtin_amdgcn_readfirstlane(ocw * 500 + ic * 25);
#pragma unroll
    for (int k = 0; k < 25; ++k) w[k] = w2[woff + k];
}

__device__ __forceinline__ void fma25(const float (&w)[25], const float (&patch)[36],
                                      float (&a)[4]) {
#pragma unroll
    for (int ky = 0; ky < 5; ++ky)
#pragma unroll
        for (int kx = 0; kx < 5; ++kx) {
            float wv = w[ky * 5 + kx];
            a[0] += patch[ky * 6 + kx] * wv;
            a[1] += patch[ky * 6 + kx + 1] * wv;
            a[2] += patch[(ky + 1) * 6 + kx] * wv;
            a[3] += patch[(ky + 1) * 6 + kx + 1] * wv;
        }
}

__device__ __forceinline__ void ldpatch(float (&patch)[36], const float* ip) {
#pragma unroll
    for (int r = 0; r < 6; ++r)
#pragma unroll
        for (int c = 0; c < 3; ++c) {
            float2 v = *reinterpret_cast<const float2*>(ip + r * 12 + 2 * c);
            patch[r * 6 + 2 * c]     = v.x;
            patch[r * 6 + 2 * c + 1] = v.y;
        }
}

__global__ __launch_bounds__(256) void k_conv2(const float* __restrict__ p1,
                                               const float* __restrict__ w2,
                                               const float* __restrict__ b2,
                                               float* __restrict__ p2) {
    __shared__ float in0[4 * IMG_STRIDE];
    int b0 = blockIdx.x * 4;
    int tid = threadIdx.x;
#pragma unroll
    for (int i4 = 0; i4 < 4; ++i4) {
        const float4* src = reinterpret_cast<const float4*>(p1 + (size_t)(b0 + i4) * 2880);
        float4* dst = reinterpret_cast<float4*>(&in0[i4 * IMG_STRIDE]);
        for (int t = tid; t < 720; t += 256) dst[t] = src[t];
    }
    __syncthreads();

    int wid  = tid >> 6;        // 0..3 -> oc group base wid*13
    int lane = tid & 63;
    int img  = lane >> 4;
    int pos  = lane & 15;
    int py = pos >> 2, px = pos & 3;
    const float* ibase = &in0[img * IMG_STRIDE + 2 * py * 12 + 2 * px];
    int ocb = wid * 13;

    float acc[13][4];
#pragma unroll
    for (int j = 0; j < 13; ++j)
#pragma unroll
        for (int q = 0; q < 4; ++q) acc[j][q] = 0.f;

    float wbuf0[25], wbuf1[25];
    float patch[36];
    wload(wbuf0, w2, 0, ocb);          // prime: (ic=0, j=0) in buf0

    for (int ic = 0; ic < 20; ic += 2) {
        ldpatch(patch, ibase + ic * 144);
#pragma unroll
        for (int jj = 0; jj < 26; ++jj) {
            if (jj == 13) ldpatch(patch, ibase + (ic + 1) * 144);
            int j = (jj < 13) ? jj : jj - 13;
            int jn, icn;                     // next (ic, j) to prefetch
            if (jj < 12)      { jn = jj + 1;  icn = ic; }
            else if (jj < 25) { jn = jj - 12; icn = ic + 1; }
            else              { jn = 0;       icn = (ic + 2 < 20) ? ic + 2 : 0; }
            if ((jj & 1) == 0) {
                wload(wbuf1, w2, icn, ocb + jn);
                fma25(wbuf0, patch, acc[j]);
            } else {
                wload(wbuf0, w2, icn, ocb + jn);
                fma25(wbuf1, patch, acc[j]);
            }
        }
    }

#pragma unroll
    for (int j = 0; j < 13; ++j) {
        int oc = ocb + j;
        if (oc < 50) {
            float bias = b2[oc];
            float m = fmaxf(fmaxf(fmaxf(trunc13(acc[j][0] + bias), 0.f),
                                  fmaxf(trunc13(acc[j][1] + bias), 0.f)),
                            fmaxf(fmaxf(trunc13(acc[j][2] + bias), 0.f),
                                  fmaxf(trunc13(acc[j][3] + bias), 0.f)));
            p2[(size_t)(b0 + img) * 800 + oc * 16 + pos] = m;
        }
    }
}

// ---------------------------------------------------------------------------
// K3: fc1  H = relu(trunc(A @ W^T + b))   A:[4096,800] W:[500,800] -> [4096,500]
// ---------------------------------------------------------------------------
__global__ __launch_bounds__(256) void k_fc1(const float* __restrict__ A,
                                             const float* __restrict__ W,
                                             const float* __restrict__ bias,
                                             float* __restrict__ H) {
    __shared__ __align__(16) float As[16][68];
    __shared__ __align__(16) float Ws[16][68];
    int tid = threadIdx.x;
    int tx = tid & 15;
    int ty = tid >> 4;
    int i0 = blockIdx.x * 64;
    int n0 = blockIdx.y * 64;
    int tm = tid & 15;
    int tn = tid >> 4;
    float acc[4][4] = {};

    for (int k0 = 0; k0 < 800; k0 += 16) {
#pragma unroll
        for (int q = 0; q < 4; ++q) {
            int row = ty + 16 * q;
            As[tx][row] = A[(size_t)(i0 + row) * 800 + k0 + tx];
            int n = n0 + row;
            Ws[tx][row] = (n < 500) ? W[(size_t)n * 800 + k0 + tx] : 0.f;
        }
        __syncthreads();
#pragma unroll
        for (int k = 0; k < 16; ++k) {
            float4 a = *reinterpret_cast<const float4*>(&As[k][tm * 4]);
            float4 w = *reinterpret_cast<const float4*>(&Ws[k][tn * 4]);
            float av[4] = {a.x, a.y, a.z, a.w};
            float wv[4] = {w.x, w.y, w.z, w.w};
#pragma unroll
            for (int r = 0; r < 4; ++r)
#pragma unroll
                for (int c = 0; c < 4; ++c)
                    acc[r][c] += av[r] * wv[c];
        }
        __syncthreads();
    }

#pragma unroll
    for (int r = 0; r < 4; ++r) {
        int i = i0 + tm * 4 + r;
#pragma unroll
        for (int c = 0; c < 4; ++c) {
            int n = n0 + tn * 4 + c;
            if (n < 500)
                H[(size_t)i * 500 + n] = fmaxf(trunc13(acc[r][c] + bias[n]), 0.f);
        }
    }
}

// ---------------------------------------------------------------------------
// K4: fc2 (500->10) + bias + trunc + log_softmax.  One wave per row.
// ---------------------------------------------------------------------------
__global__ __launch_bounds__(256) void k_fc2(const float* __restrict__ H,
                                             const float* __restrict__ W,
                                             const float* __restrict__ bias,
                                             float* __restrict__ out) {
    int wave = threadIdx.x >> 6;
    int lane = threadIdx.x & 63;
    int i = blockIdx.x * 4 + wave;
    const float* hrow = H + (size_t)i * 500;

    float p[10];
#pragma unroll
    for (int j = 0; j < 10; ++j) p[j] = 0.f;
    for (int k = lane; k < 500; k += 64) {
        float h = hrow[k];
#pragma unroll
        for (int j = 0; j < 10; ++j) p[j] += h * W[j * 500 + k];
    }
#pragma unroll
    for (int j = 0; j < 10; ++j)
#pragma unroll
        for (int off = 32; off; off >>= 1) p[j] += __shfl_xor(p[j], off, 64);

    if (lane == 0) {
        float z[10], m = -1e30f;
#pragma unroll
        for (int j = 0; j < 10; ++j) {
            z[j] = trunc13(p[j] + bias[j]);
            m = fmaxf(m, z[j]);
        }
        float s = 0.f;
#pragma unroll
        for (int j = 0; j < 10; ++j) s += expf(z[j] - m);
        float lse = m + logf(s);
#pragma unroll
        for (int j = 0; j < 10; ++j) out[(size_t)i * 10 + j] = z[j] - lse;
    }
}

// ---------------------------------------------------------------------------
extern "C" void kernel_launch(void* const* d_in, const int* in_sizes, int n_in,
                              void* d_out, int out_size, void* d_ws, size_t ws_size,
                              hipStream_t stream) {
    const float* x   = (const float*)d_in[0];
    const float* w1  = (const float*)d_in[1];
    const float* b1  = (const float*)d_in[2];
    const float* w2  = (const float*)d_in[3];
    const float* b2  = (const float*)d_in[4];
    const float* wf1 = (const float*)d_in[5];
    const float* bf1 = (const float*)d_in[6];
    const float* wf2 = (const float*)d_in[7];
    const float* bf2 = (const float*)d_in[8];
    float* out = (float*)d_out;

    float* p1 = (float*)d_ws;                        // 4096*2880
    float* p2 = p1 + (size_t)4096 * 2880;            // 4096*800
    float* h1 = p2 + (size_t)4096 * 800;             // 4096*500

    k_conv1<<<2304, 256, 0, stream>>>(x, w1, b1, p1);
    k_conv2<<<1024, 256, 0, stream>>>(p1, w2, b2, p2);
    dim3 g3(64, 8);
    k_fc1<<<g3, 256, 0, stream>>>(p2, wf1, bf1, h1);
    k_fc2<<<1024, 256, 0, stream>>>(h1, wf2, bf2, out);
}

// Round 9
// 207.357 us; speedup vs baseline: 2.2275x; 1.7190x over previous
//
#include <hip/hip_runtime.h>

// LeNet forward, BATCH=4096. trunc = zero low 13 mantissa bits of fp32.
// conv2 via fp16 hi/lo-split MFMA (activations are fp16-exact post-trunc).
// ws layout (bytes):
//   p1h  [4096][144][24] fp16   @ 0          (28,311,552 B)
//   p2   [4096][800]    f32     @ 28311552   (13,107,200 B)
//   h1   [4096][500]    f32     @ 41418752   ( 8,192,000 B)
//   wp   [25][64][88]   fp16    @ 49610752   (   281,600 B)

typedef _Float16 v8h __attribute__((ext_vector_type(8)));
typedef float v4f __attribute__((ext_vector_type(4)));

__device__ __forceinline__ float trunc13(float v) {
    return __int_as_float(__float_as_int(v) & (int)0xFFFFE000u);
}

// ---------------------------------------------------------------------------
// K0: weight prep for conv2 MFMA.
// wp[t][oc][0..20)=hi(w2[oc][ic][t]), [32..52)=lo, rest 0.  t=ky*5+kx.
// ---------------------------------------------------------------------------
__global__ void k_wprep(const float* __restrict__ w2, _Float16* __restrict__ wp) {
    int id = blockIdx.x * 256 + threadIdx.x;
    if (id >= 1600) return;
    int t = id / 64, oc = id % 64;
    _Float16* dst = wp + (size_t)id * 88;
    for (int i = 0; i < 88; ++i) dst[i] = (_Float16)0.f;
    if (oc < 50) {
        for (int ic = 0; ic < 20; ++ic) {
            float w = w2[oc * 500 + ic * 25 + t];
            _Float16 hi = (_Float16)w;
            _Float16 lo = (_Float16)(w - (float)hi);
            dst[ic] = hi;
            dst[32 + ic] = lo;
        }
    }
}

// ---------------------------------------------------------------------------
// K1: conv1 + bias + trunc + relu + 2x2 maxpool -> fp16 [img][pos][24]
// ---------------------------------------------------------------------------
__global__ __launch_bounds__(256) void k_conv1(const float* __restrict__ x,
                                               const float* __restrict__ w1,
                                               const float* __restrict__ b1,
                                               _Float16* __restrict__ p1h) {
    __shared__ float wsm[500];
    __shared__ float bsm[20];
    int tid = threadIdx.x;
    for (int t = tid; t < 500; t += 256) wsm[t] = w1[t];
    if (tid < 20) bsm[tid] = b1[tid];
    __syncthreads();

    int gid = blockIdx.x * 256 + tid;   // 4096*144 = 2304*256 exact
    int b   = gid / 144;
    int pos = gid % 144;
    int py = pos / 12, px = pos % 12;
    const float* img = x + (size_t)b * 784;

    float patch[36];
#pragma unroll
    for (int r = 0; r < 6; ++r)
#pragma unroll
        for (int c = 0; c < 6; ++c)
            patch[r * 6 + c] = img[(2 * py + r) * 28 + 2 * px + c];

    __align__(16) _Float16 hv[24];
#pragma unroll
    for (int q = 20; q < 24; ++q) hv[q] = (_Float16)0.f;

    for (int oc = 0; oc < 20; ++oc) {
        float bias = bsm[oc];
        float s00 = bias, s01 = bias, s10 = bias, s11 = bias;
        const float* w = &wsm[oc * 25];
#pragma unroll
        for (int ky = 0; ky < 5; ++ky)
#pragma unroll
            for (int kx = 0; kx < 5; ++kx) {
                float wv = w[ky * 5 + kx];
                s00 += patch[ky * 6 + kx] * wv;
                s01 += patch[ky * 6 + kx + 1] * wv;
                s10 += patch[(ky + 1) * 6 + kx] * wv;
                s11 += patch[(ky + 1) * 6 + kx + 1] * wv;
            }
        float m = fmaxf(fmaxf(fmaxf(trunc13(s00), 0.f), fmaxf(trunc13(s01), 0.f)),
                        fmaxf(fmaxf(trunc13(s10), 0.f), fmaxf(trunc13(s11), 0.f)));
        hv[oc] = (_Float16)m;   // post-trunc relu value: exact in fp16
    }
    uint4* outp = (uint4*)(p1h + ((size_t)b * 144 + pos) * 24);
    const uint4* src = (const uint4*)hv;
    outp[0] = src[0]; outp[1] = src[1]; outp[2] = src[2];
}

// ---------------------------------------------------------------------------
// K2: conv2 via MFMA 16x16x32_f16, hi/lo weight split, fused pool epilogue.
// Block = 4 images, 4 waves; wave w = image w, all 4 oc-tiles.
// A in LDS [4img][144pix][32ic] fp16; B dbuf [2][64oc][88] fp16 (T14 staged).
// K = 25 pixels x 32 ic-pad.  acc C-layout: col=lane&15(oc), row=(kg)*4+j(pos).
// ---------------------------------------------------------------------------
#define AIMG 4608
__global__ __launch_bounds__(256) void k_conv2(const _Float16* __restrict__ p1h,
                                               const _Float16* __restrict__ wp,
                                               const float* __restrict__ b2,
                                               float* __restrict__ p2) {
    __shared__ _Float16 Al[4 * AIMG];    // 36864 B
    __shared__ _Float16 Bl[2 * 5632];    // 22528 B
    int tid = threadIdx.x;
    int b0 = blockIdx.x * 4;

    // A staging: 576 tasks (4 img x 144 pos), 48B copy + 16B zero pad each
#pragma unroll
    for (int r = 0; r < 3; ++r) {
        int task = r * 256 + tid;
        if (task < 576) {
            int img = task / 144, pos = task % 144;
            const uint4* src = (const uint4*)(p1h + ((size_t)(b0 + img) * 144 + pos) * 24);
            uint4 v0 = src[0], v1 = src[1], v2 = src[2];
            uint4* dst = (uint4*)(Al + img * AIMG + pos * 32);
            dst[0] = v0; dst[1] = v1; dst[2] = v2;
            dst[3] = make_uint4(0u, 0u, 0u, 0u);
        }
    }
    // B stage t=0: 2816 words
    {
        const uint* g = (const uint*)wp;
        uint* d = (uint*)Bl;
#pragma unroll
        for (int i = 0; i < 11; ++i) d[i * 256 + tid] = g[i * 256 + tid];
    }
    __syncthreads();

    int wid = tid >> 6, lane = tid & 63;
    int kg = lane >> 4, rr = lane & 15;
    int Y = rr >> 3, xx = rr & 7;
    const _Float16* Abase = Al + wid * AIMG;

    v4f zero = {0.f, 0.f, 0.f, 0.f};
    v4f acc[4][4];
#pragma unroll
    for (int my = 0; my < 4; ++my)
#pragma unroll
        for (int nt = 0; nt < 4; ++nt) acc[my][nt] = zero;

    for (int t = 0; t < 25; ++t) {
        int cur = t & 1;
        uint nb[11];
        if (t + 1 < 25) {                 // T14: issue next-B loads early
            const uint* g = (const uint*)(wp + (size_t)(t + 1) * 5632);
#pragma unroll
            for (int i = 0; i < 11; ++i) nb[i] = g[i * 256 + tid];
        }
        int ky = t / 5, kx = t % 5;
        v8h af[4], bh[4], bl[4];
#pragma unroll
        for (int my = 0; my < 4; ++my) {
            int y = 2 * my + Y;
            af[my] = *(const v8h*)(Abase + ((y + ky) * 12 + (xx + kx)) * 32 + kg * 8);
        }
        const _Float16* Bb = Bl + cur * 5632;
#pragma unroll
        for (int nt = 0; nt < 4; ++nt) {
            int oc = nt * 16 + rr;
            bh[nt] = *(const v8h*)(Bb + oc * 88 + kg * 8);
            bl[nt] = *(const v8h*)(Bb + oc * 88 + 32 + kg * 8);
        }
#pragma unroll
        for (int my = 0; my < 4; ++my)
#pragma unroll
            for (int nt = 0; nt < 4; ++nt) {
                acc[my][nt] = __builtin_amdgcn_mfma_f32_16x16x32_f16(af[my], bh[nt], acc[my][nt], 0, 0, 0);
                acc[my][nt] = __builtin_amdgcn_mfma_f32_16x16x32_f16(af[my], bl[nt], acc[my][nt], 0, 0, 0);
            }
        if (t + 1 < 25) {                 // write-late half of T14
            uint* d = (uint*)(Bl + (cur ^ 1) * 5632);
#pragma unroll
            for (int i = 0; i < 11; ++i) d[i * 256 + tid] = nb[i];
        }
        __syncthreads();
    }

    // epilogue: bias + trunc + relu, then 2x2 pool (lane-local + xor32)
    int imgg = b0 + wid;
#pragma unroll
    for (int nt = 0; nt < 4; ++nt) {
        int oc = nt * 16 + rr;
        float bias = (oc < 50) ? b2[oc] : 0.f;
#pragma unroll
        for (int my = 0; my < 4; ++my) {
            float z0 = fmaxf(trunc13(acc[my][nt][0] + bias), 0.f);
            float z1 = fmaxf(trunc13(acc[my][nt][1] + bias), 0.f);
            float z2 = fmaxf(trunc13(acc[my][nt][2] + bias), 0.f);
            float z3 = fmaxf(trunc13(acc[my][nt][3] + bias), 0.f);
            float s0 = fmaxf(z0, z1), s2 = fmaxf(z2, z3);
            float o0 = fmaxf(s0, __shfl_xor(s0, 32, 64));
            float o2 = fmaxf(s2, __shfl_xor(s2, 32, 64));
            if (kg < 2 && oc < 50) {
                p2[(size_t)imgg * 800 + oc * 16 + my * 4 + 2 * kg]     = o0;
                p2[(size_t)imgg * 800 + oc * 16 + my * 4 + 2 * kg + 1] = o2;
            }
        }
    }
}

// ---------------------------------------------------------------------------
// K3: fc1  H = relu(trunc(A @ W^T + b))   A:[4096,800] W:[500,800] -> [4096,500]
// ---------------------------------------------------------------------------
__global__ __launch_bounds__(256) void k_fc1(const float* __restrict__ A,
                                             const float* __restrict__ W,
                                             const float* __restrict__ bias,
                                             float* __restrict__ H) {
    __shared__ __align__(16) float As[16][68];
    __shared__ __align__(16) float Ws[16][68];
    int tid = threadIdx.x;
    int tx = tid & 15;
    int ty = tid >> 4;
    int i0 = blockIdx.x * 64;
    int n0 = blockIdx.y * 64;
    int tm = tid & 15;
    int tn = tid >> 4;
    float acc[4][4] = {};

    for (int k0 = 0; k0 < 800; k0 += 16) {
#pragma unroll
        for (int q = 0; q < 4; ++q) {
            int row = ty + 16 * q;
            As[tx][row] = A[(size_t)(i0 + row) * 800 + k0 + tx];
            int n = n0 + row;
            Ws[tx][row] = (n < 500) ? W[(size_t)n * 800 + k0 + tx] : 0.f;
        }
        __syncthreads();
#pragma unroll
        for (int k = 0; k < 16; ++k) {
            float4 a = *reinterpret_cast<const float4*>(&As[k][tm * 4]);
            float4 w = *reinterpret_cast<const float4*>(&Ws[k][tn * 4]);
            float av[4] = {a.x, a.y, a.z, a.w};
            float wv[4] = {w.x, w.y, w.z, w.w};
#pragma unroll
            for (int r = 0; r < 4; ++r)
#pragma unroll
                for (int c = 0; c < 4; ++c)
                    acc[r][c] += av[r] * wv[c];
        }
        __syncthreads();
    }

#pragma unroll
    for (int r = 0; r < 4; ++r) {
        int i = i0 + tm * 4 + r;
#pragma unroll
        for (int c = 0; c < 4; ++c) {
            int n = n0 + tn * 4 + c;
            if (n < 500)
                H[(size_t)i * 500 + n] = fmaxf(trunc13(acc[r][c] + bias[n]), 0.f);
        }
    }
}

// ---------------------------------------------------------------------------
// K4: fc2 (500->10) + bias + trunc + log_softmax.  One wave per row.
// ---------------------------------------------------------------------------
__global__ __launch_bounds__(256) void k_fc2(const float* __restrict__ H,
                                             const float* __restrict__ W,
                                             const float* __restrict__ bias,
                                             float* __restrict__ out) {
    int wave = threadIdx.x >> 6;
    int lane = threadIdx.x & 63;
    int i = blockIdx.x * 4 + wave;
    const float* hrow = H + (size_t)i * 500;

    float p[10];
#pragma unroll
    for (int j = 0; j < 10; ++j) p[j] = 0.f;
    for (int k = lane; k < 500; k += 64) {
        float h = hrow[k];
#pragma unroll
        for (int j = 0; j < 10; ++j) p[j] += h * W[j * 500 + k];
    }
#pragma unroll
    for (int j = 0; j < 10; ++j)
#pragma unroll
        for (int off = 32; off; off >>= 1) p[j] += __shfl_xor(p[j], off, 64);

    if (lane == 0) {
        float z[10], m = -1e30f;
#pragma unroll
        for (int j = 0; j < 10; ++j) {
            z[j] = trunc13(p[j] + bias[j]);
            m = fmaxf(m, z[j]);
        }
        float s = 0.f;
#pragma unroll
        for (int j = 0; j < 10; ++j) s += expf(z[j] - m);
        float lse = m + logf(s);
#pragma unroll
        for (int j = 0; j < 10; ++j) out[(size_t)i * 10 + j] = z[j] - lse;
    }
}

// ---------------------------------------------------------------------------
extern "C" void kernel_launch(void* const* d_in, const int* in_sizes, int n_in,
                              void* d_out, int out_size, void* d_ws, size_t ws_size,
                              hipStream_t stream) {
    const float* x   = (const float*)d_in[0];
    const float* w1  = (const float*)d_in[1];
    const float* b1  = (const float*)d_in[2];
    const float* w2  = (const float*)d_in[3];
    const float* b2  = (const float*)d_in[4];
    const float* wf1 = (const float*)d_in[5];
    const float* bf1 = (const float*)d_in[6];
    const float* wf2 = (const float*)d_in[7];
    const float* bf2 = (const float*)d_in[8];
    float* out = (float*)d_out;

    char* ws = (char*)d_ws;
    _Float16* p1h = (_Float16*)(ws);                    // 28,311,552 B
    float*    p2  = (float*)(ws + 28311552);            // 13,107,200 B
    float*    h1  = (float*)(ws + 41418752);            //  8,192,000 B
    _Float16* wpp = (_Float16*)(ws + 49610752);         //    281,600 B

    k_wprep<<<7, 256, 0, stream>>>(w2, wpp);
    k_conv1<<<2304, 256, 0, stream>>>(x, w1, b1, p1h);
    k_conv2<<<1024, 256, 0, stream>>>(p1h, wpp, b2, p2);
    dim3 g3(64, 8);
    k_fc1<<<g3, 256, 0, stream>>>(p2, wf1, bf1, h1);
    k_fc2<<<1024, 256, 0, stream>>>(h1, wf2, bf2, out);
}

// Round 10
// 152.044 us; speedup vs baseline: 3.0378x; 1.3638x over previous
//
#include <hip/hip_runtime.h>

// LeNet forward, BATCH=4096. trunc = zero low 13 bits of fp32 mantissa.
// conv2 AND fc1 via fp16 hi/lo-split MFMA (post-trunc activations are
// fp16-exact; weight = hi + lo fp16 pair -> two MFMAs).
// ws layout (bytes):
//   p1h  [4096][144][24] fp16 @ 0            (28,311,552)
//   p2h  [4096][800]     fp16 @ 28,311,552   ( 6,553,600)
//   h1h  [4096][512]     fp16 @ 34,865,152   ( 4,194,304)
//   wpc2 [25][64][88]    fp16 @ 39,059,456   (   281,600)
//   wpf1 [25][512][64]   fp16 @ 39,341,056   ( 1,638,400)

typedef _Float16 v8h __attribute__((ext_vector_type(8)));
typedef float v4f __attribute__((ext_vector_type(4)));

__device__ __forceinline__ float trunc13(float v) {
    return __int_as_float(__float_as_int(v) & (int)0xFFFFE000u);
}

// ---------------------------------------------------------------------------
// K0a: conv2 weight prep: wp[t][oc][0..20)=hi, [32..52)=lo, t=ky*5+kx
// ---------------------------------------------------------------------------
__global__ void k_wprep(const float* __restrict__ w2, _Float16* __restrict__ wp) {
    int id = blockIdx.x * 256 + threadIdx.x;
    if (id >= 1600) return;
    int t = id / 64, oc = id % 64;
    _Float16* dst = wp + (size_t)id * 88;
    for (int i = 0; i < 88; ++i) dst[i] = (_Float16)0.f;
    if (oc < 50) {
        for (int ic = 0; ic < 20; ++ic) {
            float w = w2[oc * 500 + ic * 25 + t];
            _Float16 hi = (_Float16)w;
            _Float16 lo = (_Float16)(w - (float)hi);
            dst[ic] = hi;
            dst[32 + ic] = lo;
        }
    }
}

// ---------------------------------------------------------------------------
// K0b: fc1 weight prep: wp1[t][oc][kk]=hi(W[oc][t*32+kk]), [32+kk]=lo
// ---------------------------------------------------------------------------
__global__ void k_w1prep(const float* __restrict__ W, _Float16* __restrict__ Bp) {
    int id = blockIdx.x * 256 + threadIdx.x;   // 25*512 = 12800
    if (id >= 12800) return;
    int t = id >> 9, oc = id & 511;
    _Float16* dst = Bp + (size_t)id * 64;
    for (int kk = 0; kk < 32; ++kk) {
        float w = (oc < 500) ? W[(size_t)oc * 800 + t * 32 + kk] : 0.f;
        _Float16 hi = (_Float16)w;
        _Float16 lo = (_Float16)(w - (float)hi);
        dst[kk] = hi;
        dst[32 + kk] = lo;
    }
}

// ---------------------------------------------------------------------------
// K1: conv1 + bias + trunc + relu + 2x2 maxpool -> fp16 [img][pos][24]
// ---------------------------------------------------------------------------
__global__ __launch_bounds__(256) void k_conv1(const float* __restrict__ x,
                                               const float* __restrict__ w1,
                                               const float* __restrict__ b1,
                                               _Float16* __restrict__ p1h) {
    __shared__ float wsm[500];
    __shared__ float bsm[20];
    int tid = threadIdx.x;
    for (int t = tid; t < 500; t += 256) wsm[t] = w1[t];
    if (tid < 20) bsm[tid] = b1[tid];
    __syncthreads();

    int gid = blockIdx.x * 256 + tid;   // 4096*144 = 2304*256 exact
    int b   = gid / 144;
    int pos = gid % 144;
    int py = pos / 12, px = pos % 12;
    const float* img = x + (size_t)b * 784;

    float patch[36];
#pragma unroll
    for (int r = 0; r < 6; ++r)
#pragma unroll
        for (int c = 0; c < 6; ++c)
            patch[r * 6 + c] = img[(2 * py + r) * 28 + 2 * px + c];

    __align__(16) _Float16 hv[24];
#pragma unroll
    for (int q = 20; q < 24; ++q) hv[q] = (_Float16)0.f;

    for (int oc = 0; oc < 20; ++oc) {
        float bias = bsm[oc];
        float s00 = bias, s01 = bias, s10 = bias, s11 = bias;
        const float* w = &wsm[oc * 25];
#pragma unroll
        for (int ky = 0; ky < 5; ++ky)
#pragma unroll
            for (int kx = 0; kx < 5; ++kx) {
                float wv = w[ky * 5 + kx];
                s00 += patch[ky * 6 + kx] * wv;
                s01 += patch[ky * 6 + kx + 1] * wv;
                s10 += patch[(ky + 1) * 6 + kx] * wv;
                s11 += patch[(ky + 1) * 6 + kx + 1] * wv;
            }
        float m = fmaxf(fmaxf(fmaxf(trunc13(s00), 0.f), fmaxf(trunc13(s01), 0.f)),
                        fmaxf(fmaxf(trunc13(s10), 0.f), fmaxf(trunc13(s11), 0.f)));
        hv[oc] = (_Float16)m;
    }
    uint4* outp = (uint4*)(p1h + ((size_t)b * 144 + pos) * 24);
    const uint4* src = (const uint4*)hv;
    outp[0] = src[0]; outp[1] = src[1]; outp[2] = src[2];
}

// ---------------------------------------------------------------------------
// K2: conv2 via MFMA 16x16x32_f16, hi/lo split, fused pool; outputs fp16 p2h.
// ---------------------------------------------------------------------------
#define AIMG 4608
__global__ __launch_bounds__(256) void k_conv2(const _Float16* __restrict__ p1h,
                                               const _Float16* __restrict__ wp,
                                               const float* __restrict__ b2,
                                               _Float16* __restrict__ p2h) {
    __shared__ _Float16 Al[4 * AIMG];    // 36864 B
    __shared__ _Float16 Bl[2 * 5632];    // 22528 B
    int tid = threadIdx.x;
    int b0 = blockIdx.x * 4;

#pragma unroll
    for (int r = 0; r < 3; ++r) {
        int task = r * 256 + tid;
        if (task < 576) {
            int img = task / 144, pos = task % 144;
            const uint4* src = (const uint4*)(p1h + ((size_t)(b0 + img) * 144 + pos) * 24);
            uint4 v0 = src[0], v1 = src[1], v2 = src[2];
            uint4* dst = (uint4*)(Al + img * AIMG + pos * 32);
            dst[0] = v0; dst[1] = v1; dst[2] = v2;
            dst[3] = make_uint4(0u, 0u, 0u, 0u);
        }
    }
    {
        const uint* g = (const uint*)wp;
        uint* d = (uint*)Bl;
#pragma unroll
        for (int i = 0; i < 11; ++i) d[i * 256 + tid] = g[i * 256 + tid];
    }
    __syncthreads();

    int wid = tid >> 6, lane = tid & 63;
    int kg = lane >> 4, rr = lane & 15;
    int Y = rr >> 3, xx = rr & 7;
    const _Float16* Abase = Al + wid * AIMG;

    v4f zero = {0.f, 0.f, 0.f, 0.f};
    v4f acc[4][4];
#pragma unroll
    for (int my = 0; my < 4; ++my)
#pragma unroll
        for (int nt = 0; nt < 4; ++nt) acc[my][nt] = zero;

    for (int t = 0; t < 25; ++t) {
        int cur = t & 1;
        uint nb[11];
        if (t + 1 < 25) {
            const uint* g = (const uint*)(wp + (size_t)(t + 1) * 5632);
#pragma unroll
            for (int i = 0; i < 11; ++i) nb[i] = g[i * 256 + tid];
        }
        int ky = t / 5, kx = t % 5;
        v8h af[4], bh[4], bl[4];
#pragma unroll
        for (int my = 0; my < 4; ++my) {
            int y = 2 * my + Y;
            af[my] = *(const v8h*)(Abase + ((y + ky) * 12 + (xx + kx)) * 32 + kg * 8);
        }
        const _Float16* Bb = Bl + cur * 5632;
#pragma unroll
        for (int nt = 0; nt < 4; ++nt) {
            int oc = nt * 16 + rr;
            bh[nt] = *(const v8h*)(Bb + oc * 88 + kg * 8);
            bl[nt] = *(const v8h*)(Bb + oc * 88 + 32 + kg * 8);
        }
#pragma unroll
        for (int my = 0; my < 4; ++my)
#pragma unroll
            for (int nt = 0; nt < 4; ++nt) {
                acc[my][nt] = __builtin_amdgcn_mfma_f32_16x16x32_f16(af[my], bh[nt], acc[my][nt], 0, 0, 0);
                acc[my][nt] = __builtin_amdgcn_mfma_f32_16x16x32_f16(af[my], bl[nt], acc[my][nt], 0, 0, 0);
            }
        if (t + 1 < 25) {
            uint* d = (uint*)(Bl + (cur ^ 1) * 5632);
#pragma unroll
            for (int i = 0; i < 11; ++i) d[i * 256 + tid] = nb[i];
        }
        __syncthreads();
    }

    int imgg = b0 + wid;
#pragma unroll
    for (int nt = 0; nt < 4; ++nt) {
        int oc = nt * 16 + rr;
        float bias = (oc < 50) ? b2[oc] : 0.f;
#pragma unroll
        for (int my = 0; my < 4; ++my) {
            float z0 = fmaxf(trunc13(acc[my][nt][0] + bias), 0.f);
            float z1 = fmaxf(trunc13(acc[my][nt][1] + bias), 0.f);
            float z2 = fmaxf(trunc13(acc[my][nt][2] + bias), 0.f);
            float z3 = fmaxf(trunc13(acc[my][nt][3] + bias), 0.f);
            float s0 = fmaxf(z0, z1), s2 = fmaxf(z2, z3);
            float o0 = fmaxf(s0, __shfl_xor(s0, 32, 64));
            float o2 = fmaxf(s2, __shfl_xor(s2, 32, 64));
            if (kg < 2 && oc < 50) {
                p2h[(size_t)imgg * 800 + oc * 16 + my * 4 + 2 * kg]     = (_Float16)o0;
                p2h[(size_t)imgg * 800 + oc * 16 + my * 4 + 2 * kg + 1] = (_Float16)o2;
            }
        }
    }
}

// ---------------------------------------------------------------------------
// K3: fc1 via MFMA 16x16x32_f16, hi/lo split.  A:[4096,800]fp16 -> H fp16.
// BM=128 BN=64 BK=32, grid 32x8, 4 waves; XOR-swizzled LDS (conflict-free);
// T14 reg-staged double buffer, one barrier/iter.
// ---------------------------------------------------------------------------
__global__ __launch_bounds__(256) void k_fc1(const _Float16* __restrict__ Ah,
                                             const _Float16* __restrict__ Bp,
                                             const float* __restrict__ bias,
                                             _Float16* __restrict__ Hh) {
    __shared__ _Float16 Al[2][4096];   // 128 x 32, granule-swizzled
    __shared__ _Float16 Bl[2][4096];   // 64 x 64 (32hi|32lo), granule-swizzled
    int tid = threadIdx.x;
    int i0 = blockIdx.x * 128, n0 = blockIdx.y * 64;
    int wid = tid >> 6, lane = tid & 63;
    int rr = lane & 15, kg = lane >> 4;

    // staging chunk decomposition (16B granules)
    int ca0 = tid, ca1 = tid + 256;          // A: r=c>>2, q=c&3
    int ra0_ = ca0 >> 2, qa0 = ca0 & 3, ra1_ = ca1 >> 2, qa1 = ca1 & 3;
    int cb0 = tid, cb1 = tid + 256;          // B: r=c>>3, q=c&7
    int rb0_ = cb0 >> 3, qb0 = cb0 & 7, rb1_ = cb1 >> 3, qb1 = cb1 & 7;
    int aw0 = (ra0_ * 4 + (qa0 ^ ((ra0_ >> 1) & 3))) * 8;
    int aw1 = (ra1_ * 4 + (qa1 ^ ((ra1_ >> 1) & 3))) * 8;
    int bw0 = (rb0_ * 8 + (qb0 ^ (rb0_ & 7))) * 8;
    int bw1 = (rb1_ * 8 + (qb1 ^ (rb1_ & 7))) * 8;

    uint4 xa0, xa1, xb0, xb1;
    auto loadT = [&](int t) {
        xa0 = *(const uint4*)(Ah + (size_t)(i0 + ra0_) * 800 + t * 32 + qa0 * 8);
        xa1 = *(const uint4*)(Ah + (size_t)(i0 + ra1_) * 800 + t * 32 + qa1 * 8);
        const uint4* g = (const uint4*)(Bp + ((size_t)t * 512 + n0) * 64);
        xb0 = g[cb0]; xb1 = g[cb1];
    };
    auto writeT = [&](int buf) {
        *(uint4*)(&Al[buf][aw0]) = xa0;
        *(uint4*)(&Al[buf][aw1]) = xa1;
        *(uint4*)(&Bl[buf][bw0]) = xb0;
        *(uint4*)(&Bl[buf][bw1]) = xb1;
    };

    // fragment read offsets (swizzled)
    int aoff[2], bhoff[4], bloff[4];
#pragma unroll
    for (int mf = 0; mf < 2; ++mf) {
        int r = wid * 32 + mf * 16 + rr;
        aoff[mf] = (r * 4 + (kg ^ ((rr >> 1) & 3))) * 8;
    }
#pragma unroll
    for (int nf = 0; nf < 4; ++nf) {
        int r = nf * 16 + rr;
        bhoff[nf] = (r * 8 + (kg ^ (rr & 7))) * 8;
        bloff[nf] = (r * 8 + ((kg + 4) ^ (rr & 7))) * 8;
    }

    v4f zero = {0.f, 0.f, 0.f, 0.f};
    v4f acc[2][4];
#pragma unroll
    for (int mf = 0; mf < 2; ++mf)
#pragma unroll
        for (int nf = 0; nf < 4; ++nf) acc[mf][nf] = zero;

    loadT(0);
    writeT(0);
    __syncthreads();

    for (int t = 0; t < 25; ++t) {
        int cur = t & 1;
        if (t < 24) loadT(t + 1);
        v8h af[2], bh[4], bl[4];
#pragma unroll
        for (int mf = 0; mf < 2; ++mf) af[mf] = *(const v8h*)(&Al[cur][aoff[mf]]);
#pragma unroll
        for (int nf = 0; nf < 4; ++nf) {
            bh[nf] = *(const v8h*)(&Bl[cur][bhoff[nf]]);
            bl[nf] = *(const v8h*)(&Bl[cur][bloff[nf]]);
        }
#pragma unroll
        for (int mf = 0; mf < 2; ++mf)
#pragma unroll
            for (int nf = 0; nf < 4; ++nf) {
                acc[mf][nf] = __builtin_amdgcn_mfma_f32_16x16x32_f16(af[mf], bh[nf], acc[mf][nf], 0, 0, 0);
                acc[mf][nf] = __builtin_amdgcn_mfma_f32_16x16x32_f16(af[mf], bl[nf], acc[mf][nf], 0, 0, 0);
            }
        if (t < 24) writeT(cur ^ 1);
        __syncthreads();
    }

#pragma unroll
    for (int mf = 0; mf < 2; ++mf)
#pragma unroll
        for (int nf = 0; nf < 4; ++nf) {
            int col = n0 + nf * 16 + rr;
            float bs = bias[col < 500 ? col : 0];
#pragma unroll
            for (int j = 0; j < 4; ++j) {
                int row = i0 + wid * 32 + mf * 16 + kg * 4 + j;
                float v = fmaxf(trunc13(acc[mf][nf][j] + bs), 0.f);
                if (col < 500) Hh[(size_t)row * 512 + col] = (_Float16)v;
            }
        }
}

// ---------------------------------------------------------------------------
// K4: fc2 (500->10) + bias + trunc + log_softmax.  One wave per row, fp16 H.
// ---------------------------------------------------------------------------
__global__ __launch_bounds__(256) void k_fc2(const _Float16* __restrict__ Hh,
                                             const float* __restrict__ W,
                                             const float* __restrict__ bias,
                                             float* __restrict__ out) {
    int wave = threadIdx.x >> 6;
    int lane = threadIdx.x & 63;
    int i = blockIdx.x * 4 + wave;
    const _Float16* hrow = Hh + (size_t)i * 512;

    float p[10];
#pragma unroll
    for (int j = 0; j < 10; ++j) p[j] = 0.f;
    for (int k = lane; k < 500; k += 64) {
        float h = (float)hrow[k];
#pragma unroll
        for (int j = 0; j < 10; ++j) p[j] += h * W[j * 500 + k];
    }
#pragma unroll
    for (int j = 0; j < 10; ++j)
#pragma unroll
        for (int off = 32; off; off >>= 1) p[j] += __shfl_xor(p[j], off, 64);

    if (lane == 0) {
        float z[10], m = -1e30f;
#pragma unroll
        for (int j = 0; j < 10; ++j) {
            z[j] = trunc13(p[j] + bias[j]);
            m = fmaxf(m, z[j]);
        }
        float s = 0.f;
#pragma unroll
        for (int j = 0; j < 10; ++j) s += expf(z[j] - m);
        float lse = m + logf(s);
#pragma unroll
        for (int j = 0; j < 10; ++j) out[(size_t)i * 10 + j] = z[j] - lse;
    }
}

// ---------------------------------------------------------------------------
extern "C" void kernel_launch(void* const* d_in, const int* in_sizes, int n_in,
                              void* d_out, int out_size, void* d_ws, size_t ws_size,
                              hipStream_t stream) {
    const float* x   = (const float*)d_in[0];
    const float* w1  = (const float*)d_in[1];
    const float* b1  = (const float*)d_in[2];
    const float* w2  = (const float*)d_in[3];
    const float* b2  = (const float*)d_in[4];
    const float* wf1 = (const float*)d_in[5];
    const float* bf1 = (const float*)d_in[6];
    const float* wf2 = (const float*)d_in[7];
    const float* bf2 = (const float*)d_in[8];
    float* out = (float*)d_out;

    char* ws = (char*)d_ws;
    _Float16* p1h  = (_Float16*)(ws);                   // 28,311,552
    _Float16* p2h  = (_Float16*)(ws + 28311552);        //  6,553,600
    _Float16* h1h  = (_Float16*)(ws + 34865152);        //  4,194,304
    _Float16* wpc2 = (_Float16*)(ws + 39059456);        //    281,600
    _Float16* wpf1 = (_Float16*)(ws + 39341056);        //  1,638,400

    k_wprep<<<7, 256, 0, stream>>>(w2, wpc2);
    k_w1prep<<<50, 256, 0, stream>>>(wf1, wpf1);
    k_conv1<<<2304, 256, 0, stream>>>(x, w1, b1, p1h);
    k_conv2<<<1024, 256, 0, stream>>>(p1h, wpc2, b2, p2h);
    dim3 g3(32, 8);
    k_fc1<<<g3, 256, 0, stream>>>(p2h, wpf1, bf1, h1h);
    k_fc2<<<1024, 256, 0, stream>>>(h1h, wf2, bf2, out);
}

// Round 11
// 145.471 us; speedup vs baseline: 3.1751x; 1.0452x over previous
//
#include <hip/hip_runtime.h>

// LeNet forward, BATCH=4096. trunc = zero low 13 bits of fp32 mantissa.
// conv2 & fc1 via fp16 hi/lo-split MFMA. conv2 packs hi/lo INTO K:
// K-sequence = 25 pixels x 40 slots [a*w_hi(ic0..19) | a*w_lo(ic0..19)],
// padded to 1024 = 32 K-steps of 32. A duplicated per-pixel [40] layout.
// ws layout (bytes):
//   p1h  [4096][144][40] fp16 @ 0            (47,185,920)
//   p2h  [4096][800]     fp16 @ 47,185,920   ( 6,553,600)
//   h1h  [4096][512]     fp16 @ 53,739,520   ( 4,194,304)
//   wpc2 [32][64][32]    fp16 @ 57,933,824   (   131,072)
//   wpf1 [25][512][64]   fp16 @ 58,064,896   ( 1,638,400)

typedef _Float16 v8h __attribute__((ext_vector_type(8)));
typedef float v4f __attribute__((ext_vector_type(4)));

__device__ __forceinline__ float trunc13(float v) {
    return __int_as_float(__float_as_int(v) & (int)0xFFFFE000u);
}

// ---------------------------------------------------------------------------
// K0a: conv2 packed weights wp[t][oc][s]:  k = t*32+s, o=k/8, pix=o/5,
// oi=o%5, r=oi*8+(s&7): r<20 -> hi(w[oc][r][pix]); r>=20 -> lo(w[oc][r-20][pix]).
// pix>=25 or oc>=50 -> 0.
// ---------------------------------------------------------------------------
__global__ void k_wprep(const float* __restrict__ w2, _Float16* __restrict__ wp) {
    int id = blockIdx.x * 256 + threadIdx.x;
    if (id >= 2048) return;
    int t = id >> 6, oc = id & 63;
    _Float16* dst = wp + (size_t)id * 32;
    for (int s = 0; s < 32; ++s) {
        int kg = s >> 3, j = s & 7;
        int o = 4 * t + kg;
        int pix = (o * 205) >> 10;          // /5, valid for o<128
        int oi = o - 5 * pix;
        int r = oi * 8 + j;
        _Float16 v = (_Float16)0.f;
        if (pix < 25 && oc < 50) {
            int ic = (r < 20) ? r : r - 20;
            float w = w2[oc * 500 + ic * 25 + pix];
            _Float16 hi = (_Float16)w;
            v = (r < 20) ? hi : (_Float16)(w - (float)hi);
        }
        dst[s] = v;
    }
}

// ---------------------------------------------------------------------------
// K0b: fc1 weight prep: wp1[t][oc][kk]=hi(W[oc][t*32+kk]), [32+kk]=lo
// ---------------------------------------------------------------------------
__global__ void k_w1prep(const float* __restrict__ W, _Float16* __restrict__ Bp) {
    int id = blockIdx.x * 256 + threadIdx.x;   // 25*512 = 12800
    if (id >= 12800) return;
    int t = id >> 9, oc = id & 511;
    _Float16* dst = Bp + (size_t)id * 64;
    for (int kk = 0; kk < 32; ++kk) {
        float w = (oc < 500) ? W[(size_t)oc * 800 + t * 32 + kk] : 0.f;
        _Float16 hi = (_Float16)w;
        _Float16 lo = (_Float16)(w - (float)hi);
        dst[kk] = hi;
        dst[32 + kk] = lo;
    }
}

// ---------------------------------------------------------------------------
// K1: conv1 + bias + trunc + relu + 2x2 maxpool -> fp16 [img][pos][40]
// (activations duplicated at +20 for conv2's fused hi/lo K packing)
// ---------------------------------------------------------------------------
__global__ __launch_bounds__(256) void k_conv1(const float* __restrict__ x,
                                               const float* __restrict__ w1,
                                               const float* __restrict__ b1,
                                               _Float16* __restrict__ p1h) {
    __shared__ float wsm[500];
    __shared__ float bsm[20];
    int tid = threadIdx.x;
    for (int t = tid; t < 500; t += 256) wsm[t] = w1[t];
    if (tid < 20) bsm[tid] = b1[tid];
    __syncthreads();

    int gid = blockIdx.x * 256 + tid;   // 4096*144 = 2304*256 exact
    int b   = gid / 144;
    int pos = gid % 144;
    int py = pos / 12, px = pos % 12;
    const float* img = x + (size_t)b * 784;

    float patch[36];
#pragma unroll
    for (int r = 0; r < 6; ++r)
#pragma unroll
        for (int c = 0; c < 6; ++c)
            patch[r * 6 + c] = img[(2 * py + r) * 28 + 2 * px + c];

    __align__(16) _Float16 hv[40];

    for (int oc = 0; oc < 20; ++oc) {
        float bias = bsm[oc];
        float s00 = bias, s01 = bias, s10 = bias, s11 = bias;
        const float* w = &wsm[oc * 25];
#pragma unroll
        for (int ky = 0; ky < 5; ++ky)
#pragma unroll
            for (int kx = 0; kx < 5; ++kx) {
                float wv = w[ky * 5 + kx];
                s00 += patch[ky * 6 + kx] * wv;
                s01 += patch[ky * 6 + kx + 1] * wv;
                s10 += patch[(ky + 1) * 6 + kx] * wv;
                s11 += patch[(ky + 1) * 6 + kx + 1] * wv;
            }
        float m = fmaxf(fmaxf(fmaxf(trunc13(s00), 0.f), fmaxf(trunc13(s01), 0.f)),
                        fmaxf(fmaxf(trunc13(s10), 0.f), fmaxf(trunc13(s11), 0.f)));
        _Float16 h = (_Float16)m;
        hv[oc] = h;
        hv[oc + 20] = h;
    }
    uint4* outp = (uint4*)(p1h + ((size_t)b * 144 + pos) * 40);
    const uint4* src = (const uint4*)hv;
#pragma unroll
    for (int i = 0; i < 5; ++i) outp[i] = src[i];
}

// ---------------------------------------------------------------------------
// K2: conv2 via MFMA 16x16x32_f16, fused hi/lo-in-K, fused pool epilogue.
// Block = 4 images, 4 waves (wave = image, 4 M-tiles). A staged ONCE
// (156-pixel-slot stride, rows 144+ zeroed for the t=31 tail). B 4KB tiles
// double-buffered in 2-t chunks: 16 barriers, 16B/thread/tile staging.
// ---------------------------------------------------------------------------
#define AIMG2 6240   // 156 pixel slots * 40 halfs
__global__ __launch_bounds__(256) void k_conv2(const _Float16* __restrict__ p1h,
                                               const _Float16* __restrict__ wp,
                                               const float* __restrict__ b2,
                                               _Float16* __restrict__ p2h) {
    __shared__ __align__(16) _Float16 Al[4 * AIMG2];   // 49920 B
    __shared__ __align__(16) _Float16 Bl[4 * 2560];    // 20480 B  [buf2][tt2][64*40]
    int tid = threadIdx.x;
    int b0 = blockIdx.x * 4;

    // A staging: 4 img x 720 uint4 copy + 60 uint4 zero pad each
    {
        const uint4* src = (const uint4*)(p1h + (size_t)b0 * 5760);
        uint4* dst = (uint4*)Al;
        uint4 z = make_uint4(0u, 0u, 0u, 0u);
        for (int i = tid; i < 3120; i += 256) {
            int img = i / 780, r = i - img * 780;
            dst[i] = (r < 720) ? src[img * 720 + r] : z;
        }
    }
    const uint4* gwp = (const uint4*)wp;   // tile t = 256 uint4 @ t*256
    // B stage chunk 0 (t=0,1) into buf0
    {
        uint4 v0 = gwp[tid];
        uint4 v1 = gwp[256 + tid];
        int w0 = (tid >> 2) * 40 + (tid & 3) * 8;
        *(uint4*)(&Bl[w0]) = v0;
        *(uint4*)(&Bl[w0 + 2560]) = v1;
    }
    __syncthreads();

    int wid = tid >> 6, lane = tid & 63;
    int kg = lane >> 4, rr = lane & 15;
    int Y = rr >> 3, xx = rr & 7;
    const _Float16* Ab = Al + wid * AIMG2;
    const _Float16* abase[4];
#pragma unroll
    for (int my = 0; my < 4; ++my)
        abase[my] = Ab + ((2 * my + Y) * 12 + xx) * 40;
    int bofs = rr * 40 + kg * 8;

    v4f acc[4][4];
#pragma unroll
    for (int my = 0; my < 4; ++my)
#pragma unroll
        for (int nt = 0; nt < 4; ++nt) acc[my][nt] = (v4f){0.f, 0.f, 0.f, 0.f};

    for (int ch = 0; ch < 16; ++ch) {
        uint4 nb0, nb1;
        if (ch < 15) {                       // T14: issue next-chunk loads early
            nb0 = gwp[(2 * ch + 2) * 256 + tid];
            nb1 = gwp[(2 * ch + 3) * 256 + tid];
        }
#pragma unroll
        for (int tt = 0; tt < 2; ++tt) {
            int t = 2 * ch + tt;
            int o = 4 * t + kg;
            int pix = (o * 205) >> 10;       // /5
            int oi = o - 5 * pix;
            int ky = (pix * 205) >> 10;      // /5
            int kx = pix - 5 * ky;
            int aofs = (ky * 12 + kx) * 40 + oi * 8;
            v8h af[4];
#pragma unroll
            for (int my = 0; my < 4; ++my)
                af[my] = *(const v8h*)(abase[my] + aofs);
            const _Float16* Bb = Bl + ((ch & 1) * 2 + tt) * 2560 + bofs;
            v8h bv[4];
#pragma unroll
            for (int nt = 0; nt < 4; ++nt)
                bv[nt] = *(const v8h*)(Bb + nt * 640);
#pragma unroll
            for (int my = 0; my < 4; ++my)
#pragma unroll
                for (int nt = 0; nt < 4; ++nt)
                    acc[my][nt] = __builtin_amdgcn_mfma_f32_16x16x32_f16(af[my], bv[nt], acc[my][nt], 0, 0, 0);
        }
        if (ch < 15) {                       // write-late half of T14
            int w0 = (((ch & 1) ^ 1) * 2) * 2560 + (tid >> 2) * 40 + (tid & 3) * 8;
            *(uint4*)(&Bl[w0]) = nb0;
            *(uint4*)(&Bl[w0 + 2560]) = nb1;
        }
        __syncthreads();
    }

    // epilogue: bias + trunc + relu, 2x2 pool (lane-local + xor32) -> fp16
    int imgg = b0 + wid;
#pragma unroll
    for (int nt = 0; nt < 4; ++nt) {
        int oc = nt * 16 + rr;
        float bias = (oc < 50) ? b2[oc] : 0.f;
#pragma unroll
        for (int my = 0; my < 4; ++my) {
            float z0 = fmaxf(trunc13(acc[my][nt][0] + bias), 0.f);
            float z1 = fmaxf(trunc13(acc[my][nt][1] + bias), 0.f);
            float z2 = fmaxf(trunc13(acc[my][nt][2] + bias), 0.f);
            float z3 = fmaxf(trunc13(acc[my][nt][3] + bias), 0.f);
            float s0 = fmaxf(z0, z1), s2 = fmaxf(z2, z3);
            float o0 = fmaxf(s0, __shfl_xor(s0, 32, 64));
            float o2 = fmaxf(s2, __shfl_xor(s2, 32, 64));
            if (kg < 2 && oc < 50) {
                p2h[(size_t)imgg * 800 + oc * 16 + my * 4 + 2 * kg]     = (_Float16)o0;
                p2h[(size_t)imgg * 800 + oc * 16 + my * 4 + 2 * kg + 1] = (_Float16)o2;
            }
        }
    }
}

// ---------------------------------------------------------------------------
// K3: fc1 via MFMA 16x16x32_f16, hi/lo split.  A:[4096,800]fp16 -> H fp16.
// BM=128 BN=64 BK=32, grid 32x8, 4 waves; XOR-swizzled LDS; T14 dbuf.
// ---------------------------------------------------------------------------
__global__ __launch_bounds__(256) void k_fc1(const _Float16* __restrict__ Ah,
                                             const _Float16* __restrict__ Bp,
                                             const float* __restrict__ bias,
                                             _Float16* __restrict__ Hh) {
    __shared__ _Float16 Al[2][4096];
    __shared__ _Float16 Bl[2][4096];
    int tid = threadIdx.x;
    int i0 = blockIdx.x * 128, n0 = blockIdx.y * 64;
    int wid = tid >> 6, lane = tid & 63;
    int rr = lane & 15, kg = lane >> 4;

    int ca0 = tid, ca1 = tid + 256;
    int ra0_ = ca0 >> 2, qa0 = ca0 & 3, ra1_ = ca1 >> 2, qa1 = ca1 & 3;
    int cb0 = tid, cb1 = tid + 256;
    int rb0_ = cb0 >> 3, qb0 = cb0 & 7, rb1_ = cb1 >> 3, qb1 = cb1 & 7;
    int aw0 = (ra0_ * 4 + (qa0 ^ ((ra0_ >> 1) & 3))) * 8;
    int aw1 = (ra1_ * 4 + (qa1 ^ ((ra1_ >> 1) & 3))) * 8;
    int bw0 = (rb0_ * 8 + (qb0 ^ (rb0_ & 7))) * 8;
    int bw1 = (rb1_ * 8 + (qb1 ^ (rb1_ & 7))) * 8;

    uint4 xa0, xa1, xb0, xb1;
    auto loadT = [&](int t) {
        xa0 = *(const uint4*)(Ah + (size_t)(i0 + ra0_) * 800 + t * 32 + qa0 * 8);
        xa1 = *(const uint4*)(Ah + (size_t)(i0 + ra1_) * 800 + t * 32 + qa1 * 8);
        const uint4* g = (const uint4*)(Bp + ((size_t)t * 512 + n0) * 64);
        xb0 = g[cb0]; xb1 = g[cb1];
    };
    auto writeT = [&](int buf) {
        *(uint4*)(&Al[buf][aw0]) = xa0;
        *(uint4*)(&Al[buf][aw1]) = xa1;
        *(uint4*)(&Bl[buf][bw0]) = xb0;
        *(uint4*)(&Bl[buf][bw1]) = xb1;
    };

    int aoff[2], bhoff[4], bloff[4];
#pragma unroll
    for (int mf = 0; mf < 2; ++mf) {
        int r = wid * 32 + mf * 16 + rr;
        aoff[mf] = (r * 4 + (kg ^ ((rr >> 1) & 3))) * 8;
    }
#pragma unroll
    for (int nf = 0; nf < 4; ++nf) {
        int r = nf * 16 + rr;
        bhoff[nf] = (r * 8 + (kg ^ (rr & 7))) * 8;
        bloff[nf] = (r * 8 + ((kg + 4) ^ (rr & 7))) * 8;
    }

    v4f zero = {0.f, 0.f, 0.f, 0.f};
    v4f acc[2][4];
#pragma unroll
    for (int mf = 0; mf < 2; ++mf)
#pragma unroll
        for (int nf = 0; nf < 4; ++nf) acc[mf][nf] = zero;

    loadT(0);
    writeT(0);
    __syncthreads();

    for (int t = 0; t < 25; ++t) {
        int cur = t & 1;
        if (t < 24) loadT(t + 1);
        v8h af[2], bh[4], bl[4];
#pragma unroll
        for (int mf = 0; mf < 2; ++mf) af[mf] = *(const v8h*)(&Al[cur][aoff[mf]]);
#pragma unroll
        for (int nf = 0; nf < 4; ++nf) {
            bh[nf] = *(const v8h*)(&Bl[cur][bhoff[nf]]);
            bl[nf] = *(const v8h*)(&Bl[cur][bloff[nf]]);
        }
#pragma unroll
        for (int mf = 0; mf < 2; ++mf)
#pragma unroll
            for (int nf = 0; nf < 4; ++nf) {
                acc[mf][nf] = __builtin_amdgcn_mfma_f32_16x16x32_f16(af[mf], bh[nf], acc[mf][nf], 0, 0, 0);
                acc[mf][nf] = __builtin_amdgcn_mfma_f32_16x16x32_f16(af[mf], bl[nf], acc[mf][nf], 0, 0, 0);
            }
        if (t < 24) writeT(cur ^ 1);
        __syncthreads();
    }

#pragma unroll
    for (int mf = 0; mf < 2; ++mf)
#pragma unroll
        for (int nf = 0; nf < 4; ++nf) {
            int col = n0 + nf * 16 + rr;
            float bs = bias[col < 500 ? col : 0];
#pragma unroll
            for (int j = 0; j < 4; ++j) {
                int row = i0 + wid * 32 + mf * 16 + kg * 4 + j;
                float v = fmaxf(trunc13(acc[mf][nf][j] + bs), 0.f);
                if (col < 500) Hh[(size_t)row * 512 + col] = (_Float16)v;
            }
        }
}

// ---------------------------------------------------------------------------
// K4: fc2 (500->10) + bias + trunc + log_softmax.  One wave per row, fp16 H.
// ---------------------------------------------------------------------------
__global__ __launch_bounds__(256) void k_fc2(const _Float16* __restrict__ Hh,
                                             const float* __restrict__ W,
                                             const float* __restrict__ bias,
                                             float* __restrict__ out) {
    int wave = threadIdx.x >> 6;
    int lane = threadIdx.x & 63;
    int i = blockIdx.x * 4 + wave;
    const _Float16* hrow = Hh + (size_t)i * 512;

    float p[10];
#pragma unroll
    for (int j = 0; j < 10; ++j) p[j] = 0.f;
    for (int k = lane; k < 500; k += 64) {
        float h = (float)hrow[k];
#pragma unroll
        for (int j = 0; j < 10; ++j) p[j] += h * W[j * 500 + k];
    }
#pragma unroll
    for (int j = 0; j < 10; ++j)
#pragma unroll
        for (int off = 32; off; off >>= 1) p[j] += __shfl_xor(p[j], off, 64);

    if (lane == 0) {
        float z[10], m = -1e30f;
#pragma unroll
        for (int j = 0; j < 10; ++j) {
            z[j] = trunc13(p[j] + bias[j]);
            m = fmaxf(m, z[j]);
        }
        float s = 0.f;
#pragma unroll
        for (int j = 0; j < 10; ++j) s += expf(z[j] - m);
        float lse = m + logf(s);
#pragma unroll
        for (int j = 0; j < 10; ++j) out[(size_t)i * 10 + j] = z[j] - lse;
    }
}

// ---------------------------------------------------------------------------
extern "C" void kernel_launch(void* const* d_in, const int* in_sizes, int n_in,
                              void* d_out, int out_size, void* d_ws, size_t ws_size,
                              hipStream_t stream) {
    const float* x   = (const float*)d_in[0];
    const float* w1  = (const float*)d_in[1];
    const float* b1  = (const float*)d_in[2];
    const float* w2  = (const float*)d_in[3];
    const float* b2  = (const float*)d_in[4];
    const float* wf1 = (const float*)d_in[5];
    const float* bf1 = (const float*)d_in[6];
    const float* wf2 = (const float*)d_in[7];
    const float* bf2 = (const float*)d_in[8];
    float* out = (float*)d_out;

    char* ws = (char*)d_ws;
    _Float16* p1h  = (_Float16*)(ws);                   // 47,185,920
    _Float16* p2h  = (_Float16*)(ws + 47185920);        //  6,553,600
    _Float16* h1h  = (_Float16*)(ws + 53739520);        //  4,194,304
    _Float16* wpc2 = (_Float16*)(ws + 57933824);        //    131,072
    _Float16* wpf1 = (_Float16*)(ws + 58064896);        //  1,638,400

    k_wprep<<<8, 256, 0, stream>>>(w2, wpc2);
    k_w1prep<<<50, 256, 0, stream>>>(wf1, wpf1);
    k_conv1<<<2304, 256, 0, stream>>>(x, w1, b1, p1h);
    k_conv2<<<1024, 256, 0, stream>>>(p1h, wpc2, b2, p2h);
    dim3 g3(32, 8);
    k_fc1<<<g3, 256, 0, stream>>>(p2h, wpf1, bf1, h1h);
    k_fc2<<<1024, 256, 0, stream>>>(h1h, wf2, bf2, out);
}

// Round 12
// 144.633 us; speedup vs baseline: 3.1934x; 1.0058x over previous
//
#include <hip/hip_runtime.h>

// LeNet forward, BATCH=4096. trunc = zero low 13 bits of fp32 mantissa.
// conv2 & fc1 via fp16 hi/lo-split MFMA. conv2 packs hi/lo INTO K
// (K = 25 pixels x 40 slots [20 a*w_hi | 20 a*w_lo], pad 1024 = 32 steps);
// B (128 KB, shared by all blocks) is read straight from L2 each step --
// no B staging, no K-loop barriers.
// ws layout (bytes):
//   p1h  [4096][144][40] fp16 @ 0            (47,185,920)
//   p2h  [4096][800]     fp16 @ 47,185,920   ( 6,553,600)
//   h1h  [4096][512]     fp16 @ 53,739,520   ( 4,194,304)
//   wpc2 [32][64][32]    fp16 @ 57,933,824   (   131,072)
//   wpf1 [25][512][64]   fp16 @ 58,064,896   ( 1,638,400)

typedef _Float16 v8h __attribute__((ext_vector_type(8)));
typedef float v4f __attribute__((ext_vector_type(4)));

__device__ __forceinline__ float trunc13(float v) {
    return __int_as_float(__float_as_int(v) & (int)0xFFFFE000u);
}

// ---------------------------------------------------------------------------
// K0a: conv2 packed weights wp[t][oc][s]:  k=t*32+s, o=4t+(s>>3), pix=o/5,
// oi=o%5, r=oi*8+(s&7): r<20 -> hi(w[oc][r][pix]); else lo(w[oc][r-20][pix]).
// ---------------------------------------------------------------------------
__global__ void k_wprep(const float* __restrict__ w2, _Float16* __restrict__ wp) {
    int id = blockIdx.x * 256 + threadIdx.x;
    if (id >= 2048) return;
    int t = id >> 6, oc = id & 63;
    _Float16* dst = wp + (size_t)id * 32;
    for (int s = 0; s < 32; ++s) {
        int kg = s >> 3, j = s & 7;
        int o = 4 * t + kg;
        int pix = (o * 205) >> 10;          // /5, valid for o<128
        int oi = o - 5 * pix;
        int r = oi * 8 + j;
        _Float16 v = (_Float16)0.f;
        if (pix < 25 && oc < 50) {
            int ic = (r < 20) ? r : r - 20;
            float w = w2[oc * 500 + ic * 25 + pix];
            _Float16 hi = (_Float16)w;
            v = (r < 20) ? hi : (_Float16)(w - (float)hi);
        }
        dst[s] = v;
    }
}

// ---------------------------------------------------------------------------
// K0b: fc1 weight prep: wp1[t][oc][kk]=hi(W[oc][t*32+kk]), [32+kk]=lo
// ---------------------------------------------------------------------------
__global__ void k_w1prep(const float* __restrict__ W, _Float16* __restrict__ Bp) {
    int id = blockIdx.x * 256 + threadIdx.x;   // 25*512 = 12800
    if (id >= 12800) return;
    int t = id >> 9, oc = id & 511;
    _Float16* dst = Bp + (size_t)id * 64;
    for (int kk = 0; kk < 32; ++kk) {
        float w = (oc < 500) ? W[(size_t)oc * 800 + t * 32 + kk] : 0.f;
        _Float16 hi = (_Float16)w;
        _Float16 lo = (_Float16)(w - (float)hi);
        dst[kk] = hi;
        dst[32 + kk] = lo;
    }
}

// ---------------------------------------------------------------------------
// K1: conv1 + bias + trunc + relu + 2x2 maxpool -> fp16 [img][pos][40]
// (activations duplicated at +20 for conv2's fused hi/lo K packing)
// ---------------------------------------------------------------------------
__global__ __launch_bounds__(256) void k_conv1(const float* __restrict__ x,
                                               const float* __restrict__ w1,
                                               const float* __restrict__ b1,
                                               _Float16* __restrict__ p1h) {
    __shared__ float wsm[500];
    __shared__ float bsm[20];
    int tid = threadIdx.x;
    for (int t = tid; t < 500; t += 256) wsm[t] = w1[t];
    if (tid < 20) bsm[tid] = b1[tid];
    __syncthreads();

    int gid = blockIdx.x * 256 + tid;   // 4096*144 = 2304*256 exact
    int b   = gid / 144;
    int pos = gid % 144;
    int py = pos / 12, px = pos % 12;
    const float* img = x + (size_t)b * 784;

    float patch[36];
#pragma unroll
    for (int r = 0; r < 6; ++r)
#pragma unroll
        for (int c = 0; c < 6; ++c)
            patch[r * 6 + c] = img[(2 * py + r) * 28 + 2 * px + c];

    __align__(16) _Float16 hv[40];

    for (int oc = 0; oc < 20; ++oc) {
        float bias = bsm[oc];
        float s00 = bias, s01 = bias, s10 = bias, s11 = bias;
        const float* w = &wsm[oc * 25];
#pragma unroll
        for (int ky = 0; ky < 5; ++ky)
#pragma unroll
            for (int kx = 0; kx < 5; ++kx) {
                float wv = w[ky * 5 + kx];
                s00 += patch[ky * 6 + kx] * wv;
                s01 += patch[ky * 6 + kx + 1] * wv;
                s10 += patch[(ky + 1) * 6 + kx] * wv;
                s11 += patch[(ky + 1) * 6 + kx + 1] * wv;
            }
        float m = fmaxf(fmaxf(fmaxf(trunc13(s00), 0.f), fmaxf(trunc13(s01), 0.f)),
                        fmaxf(fmaxf(trunc13(s10), 0.f), fmaxf(trunc13(s11), 0.f)));
        _Float16 h = (_Float16)m;
        hv[oc] = h;
        hv[oc + 20] = h;
    }
    uint4* outp = (uint4*)(p1h + ((size_t)b * 144 + pos) * 40);
    const uint4* src = (const uint4*)hv;
#pragma unroll
    for (int i = 0; i < 5; ++i) outp[i] = src[i];
}

// ---------------------------------------------------------------------------
// K2: conv2 via MFMA 16x16x32_f16, fused hi/lo-in-K, fused pool epilogue.
// Block = 4 images, 4 waves (wave = image). A staged ONCE in LDS (49.9 KB,
// 3 blocks/CU); B fragments read per-step from global (L2-hot 128 KB,
// coalesced 1KB/wave/tile). NO barriers in the K loop.
// ---------------------------------------------------------------------------
#define AIMG2 6240   // 156 pixel slots * 40 halfs
__global__ __launch_bounds__(256) void k_conv2(const _Float16* __restrict__ p1h,
                                               const _Float16* __restrict__ wp,
                                               const float* __restrict__ b2,
                                               _Float16* __restrict__ p2h) {
    __shared__ __align__(16) _Float16 Al[4 * AIMG2];   // 49920 B
    int tid = threadIdx.x;
    int b0 = blockIdx.x * 4;

    // A staging: 4 img x 720 uint4 copy + 60 uint4 zero pad each
    {
        const uint4* src = (const uint4*)(p1h + (size_t)b0 * 5760);
        uint4* dst = (uint4*)Al;
        uint4 z = make_uint4(0u, 0u, 0u, 0u);
        for (int i = tid; i < 3120; i += 256) {
            int img = i / 780, r = i - img * 780;
            dst[i] = (r < 720) ? src[img * 720 + r] : z;
        }
    }
    __syncthreads();

    int wid = tid >> 6, lane = tid & 63;
    int kg = lane >> 4, rr = lane & 15;
    int Y = rr >> 3, xx = rr & 7;
    const _Float16* Ab = Al + wid * AIMG2;
    const _Float16* abase[4];
#pragma unroll
    for (int my = 0; my < 4; ++my)
        abase[my] = Ab + ((2 * my + Y) * 12 + xx) * 40;
    const _Float16* wb = wp + rr * 32 + kg * 8;   // + t*2048 + nt*512

    v4f acc[4][4];
#pragma unroll
    for (int my = 0; my < 4; ++my)
#pragma unroll
        for (int nt = 0; nt < 4; ++nt) acc[my][nt] = (v4f){0.f, 0.f, 0.f, 0.f};

#pragma unroll 4
    for (int t = 0; t < 32; ++t) {
        int o = 4 * t + kg;
        int pix = (o * 205) >> 10;       // /5
        int oi = o - 5 * pix;
        int ky = (pix * 205) >> 10;      // /5
        int kx = pix - 5 * ky;
        int aofs = (ky * 12 + kx) * 40 + oi * 8;
        v8h af[4];
#pragma unroll
        for (int my = 0; my < 4; ++my)
            af[my] = *(const v8h*)(abase[my] + aofs);
        v8h bv[4];
#pragma unroll
        for (int nt = 0; nt < 4; ++nt)
            bv[nt] = *(const v8h*)(wb + t * 2048 + nt * 512);
#pragma unroll
        for (int my = 0; my < 4; ++my)
#pragma unroll
            for (int nt = 0; nt < 4; ++nt)
                acc[my][nt] = __builtin_amdgcn_mfma_f32_16x16x32_f16(af[my], bv[nt], acc[my][nt], 0, 0, 0);
    }

    // epilogue: bias + trunc + relu, 2x2 pool (lane-local + xor32) -> fp16
    int imgg = b0 + wid;
#pragma unroll
    for (int nt = 0; nt < 4; ++nt) {
        int oc = nt * 16 + rr;
        float bias = (oc < 50) ? b2[oc] : 0.f;
#pragma unroll
        for (int my = 0; my < 4; ++my) {
            float z0 = fmaxf(trunc13(acc[my][nt][0] + bias), 0.f);
            float z1 = fmaxf(trunc13(acc[my][nt][1] + bias), 0.f);
            float z2 = fmaxf(trunc13(acc[my][nt][2] + bias), 0.f);
            float z3 = fmaxf(trunc13(acc[my][nt][3] + bias), 0.f);
            float s0 = fmaxf(z0, z1), s2 = fmaxf(z2, z3);
            float o0 = fmaxf(s0, __shfl_xor(s0, 32, 64));
            float o2 = fmaxf(s2, __shfl_xor(s2, 32, 64));
            if (kg < 2 && oc < 50) {
                p2h[(size_t)imgg * 800 + oc * 16 + my * 4 + 2 * kg]     = (_Float16)o0;
                p2h[(size_t)imgg * 800 + oc * 16 + my * 4 + 2 * kg + 1] = (_Float16)o2;
            }
        }
    }
}

// ---------------------------------------------------------------------------
// K3: fc1 via MFMA 16x16x32_f16, hi/lo split.  A:[4096,800]fp16 -> H fp16.
// BM=128 BN=64 BK=32, grid 32x8, 4 waves; XOR-swizzled LDS; T14 dbuf.
// ---------------------------------------------------------------------------
__global__ __launch_bounds__(256) void k_fc1(const _Float16* __restrict__ Ah,
                                             const _Float16* __restrict__ Bp,
                                             const float* __restrict__ bias,
                                             _Float16* __restrict__ Hh) {
    __shared__ _Float16 Al[2][4096];
    __shared__ _Float16 Bl[2][4096];
    int tid = threadIdx.x;
    int i0 = blockIdx.x * 128, n0 = blockIdx.y * 64;
    int wid = tid >> 6, lane = tid & 63;
    int rr = lane & 15, kg = lane >> 4;

    int ca0 = tid, ca1 = tid + 256;
    int ra0_ = ca0 >> 2, qa0 = ca0 & 3, ra1_ = ca1 >> 2, qa1 = ca1 & 3;
    int cb0 = tid, cb1 = tid + 256;
    int rb0_ = cb0 >> 3, qb0 = cb0 & 7, rb1_ = cb1 >> 3, qb1 = cb1 & 7;
    int aw0 = (ra0_ * 4 + (qa0 ^ ((ra0_ >> 1) & 3))) * 8;
    int aw1 = (ra1_ * 4 + (qa1 ^ ((ra1_ >> 1) & 3))) * 8;
    int bw0 = (rb0_ * 8 + (qb0 ^ (rb0_ & 7))) * 8;
    int bw1 = (rb1_ * 8 + (qb1 ^ (rb1_ & 7))) * 8;

    uint4 xa0, xa1, xb0, xb1;
    auto loadT = [&](int t) {
        xa0 = *(const uint4*)(Ah + (size_t)(i0 + ra0_) * 800 + t * 32 + qa0 * 8);
        xa1 = *(const uint4*)(Ah + (size_t)(i0 + ra1_) * 800 + t * 32 + qa1 * 8);
        const uint4* g = (const uint4*)(Bp + ((size_t)t * 512 + n0) * 64);
        xb0 = g[cb0]; xb1 = g[cb1];
    };
    auto writeT = [&](int buf) {
        *(uint4*)(&Al[buf][aw0]) = xa0;
        *(uint4*)(&Al[buf][aw1]) = xa1;
        *(uint4*)(&Bl[buf][bw0]) = xb0;
        *(uint4*)(&Bl[buf][bw1]) = xb1;
    };

    int aoff[2], bhoff[4], bloff[4];
#pragma unroll
    for (int mf = 0; mf < 2; ++mf) {
        int r = wid * 32 + mf * 16 + rr;
        aoff[mf] = (r * 4 + (kg ^ ((rr >> 1) & 3))) * 8;
    }
#pragma unroll
    for (int nf = 0; nf < 4; ++nf) {
        int r = nf * 16 + rr;
        bhoff[nf] = (r * 8 + (kg ^ (rr & 7))) * 8;
        bloff[nf] = (r * 8 + ((kg + 4) ^ (rr & 7))) * 8;
    }

    v4f zero = {0.f, 0.f, 0.f, 0.f};
    v4f acc[2][4];
#pragma unroll
    for (int mf = 0; mf < 2; ++mf)
#pragma unroll
        for (int nf = 0; nf < 4; ++nf) acc[mf][nf] = zero;

    loadT(0);
    writeT(0);
    __syncthreads();

    for (int t = 0; t < 25; ++t) {
        int cur = t & 1;
        if (t < 24) loadT(t + 1);
        v8h af[2], bh[4], bl[4];
#pragma unroll
        for (int mf = 0; mf < 2; ++mf) af[mf] = *(const v8h*)(&Al[cur][aoff[mf]]);
#pragma unroll
        for (int nf = 0; nf < 4; ++nf) {
            bh[nf] = *(const v8h*)(&Bl[cur][bhoff[nf]]);
            bl[nf] = *(const v8h*)(&Bl[cur][bloff[nf]]);
        }
#pragma unroll
        for (int mf = 0; mf < 2; ++mf)
#pragma unroll
            for (int nf = 0; nf < 4; ++nf) {
                acc[mf][nf] = __builtin_amdgcn_mfma_f32_16x16x32_f16(af[mf], bh[nf], acc[mf][nf], 0, 0, 0);
                acc[mf][nf] = __builtin_amdgcn_mfma_f32_16x16x32_f16(af[mf], bl[nf], acc[mf][nf], 0, 0, 0);
            }
        if (t < 24) writeT(cur ^ 1);
        __syncthreads();
    }

#pragma unroll
    for (int mf = 0; mf < 2; ++mf)
#pragma unroll
        for (int nf = 0; nf < 4; ++nf) {
            int col = n0 + nf * 16 + rr;
            float bs = bias[col < 500 ? col : 0];
#pragma unroll
            for (int j = 0; j < 4; ++j) {
                int row = i0 + wid * 32 + mf * 16 + kg * 4 + j;
                float v = fmaxf(trunc13(acc[mf][nf][j] + bs), 0.f);
                if (col < 500) Hh[(size_t)row * 512 + col] = (_Float16)v;
            }
        }
}

// ---------------------------------------------------------------------------
// K4: fc2 (500->10) + bias + trunc + log_softmax.  One wave per row, fp16 H.
// ---------------------------------------------------------------------------
__global__ __launch_bounds__(256) void k_fc2(const _Float16* __restrict__ Hh,
                                             const float* __restrict__ W,
                                             const float* __restrict__ bias,
                                             float* __restrict__ out) {
    int wave = threadIdx.x >> 6;
    int lane = threadIdx.x & 63;
    int i = blockIdx.x * 4 + wave;
    const _Float16* hrow = Hh + (size_t)i * 512;

    float p[10];
#pragma unroll
    for (int j = 0; j < 10; ++j) p[j] = 0.f;
    for (int k = lane; k < 500; k += 64) {
        float h = (float)hrow[k];
#pragma unroll
        for (int j = 0; j < 10; ++j) p[j] += h * W[j * 500 + k];
    }
#pragma unroll
    for (int j = 0; j < 10; ++j)
#pragma unroll
        for (int off = 32; off; off >>= 1) p[j] += __shfl_xor(p[j], off, 64);

    if (lane == 0) {
        float z[10], m = -1e30f;
#pragma unroll
        for (int j = 0; j < 10; ++j) {
            z[j] = trunc13(p[j] + bias[j]);
            m = fmaxf(m, z[j]);
        }
        float s = 0.f;
#pragma unroll
        for (int j = 0; j < 10; ++j) s += expf(z[j] - m);
        float lse = m + logf(s);
#pragma unroll
        for (int j = 0; j < 10; ++j) out[(size_t)i * 10 + j] = z[j] - lse;
    }
}

// ---------------------------------------------------------------------------
extern "C" void kernel_launch(void* const* d_in, const int* in_sizes, int n_in,
                              void* d_out, int out_size, void* d_ws, size_t ws_size,
                              hipStream_t stream) {
    const float* x   = (const float*)d_in[0];
    const float* w1  = (const float*)d_in[1];
    const float* b1  = (const float*)d_in[2];
    const float* w2  = (const float*)d_in[3];
    const float* b2  = (const float*)d_in[4];
    const float* wf1 = (const float*)d_in[5];
    const float* bf1 = (const float*)d_in[6];
    const float* wf2 = (const float*)d_in[7];
    const float* bf2 = (const float*)d_in[8];
    float* out = (float*)d_out;

    char* ws = (char*)d_ws;
    _Float16* p1h  = (_Float16*)(ws);                   // 47,185,920
    _Float16* p2h  = (_Float16*)(ws + 47185920);        //  6,553,600
    _Float16* h1h  = (_Float16*)(ws + 53739520);        //  4,194,304
    _Float16* wpc2 = (_Float16*)(ws + 57933824);        //    131,072
    _Float16* wpf1 = (_Float16*)(ws + 58064896);        //  1,638,400

    k_wprep<<<8, 256, 0, stream>>>(w2, wpc2);
    k_w1prep<<<50, 256, 0, stream>>>(wf1, wpf1);
    k_conv1<<<2304, 256, 0, stream>>>(x, w1, b1, p1h);
    k_conv2<<<1024, 256, 0, stream>>>(p1h, wpc2, b2, p2h);
    dim3 g3(32, 8);
    k_fc1<<<g3, 256, 0, stream>>>(p2h, wpf1, bf1, h1h);
    k_fc2<<<1024, 256, 0, stream>>>(h1h, wf2, bf2, out);
}